// Round 4
// baseline (312.822 us; speedup 1.0000x reference)
//
#include <hip/hip_runtime.h>
#include <hip/hip_bf16.h>
#include <math.h>

#define DD 64
#define SEGSZ 10240
#define NSLICE 32

__device__ __forceinline__ int wave_incl_scan(int v, int lane) {
    #pragma unroll
    for (int d = 1; d < 64; d <<= 1) {
        int u = __shfl_up(v, d, 64);
        if (lane >= d) v += u;
    }
    return v;
}

// ---------------- histogram kernel (LDS-privatized, no global atomics) ----
// Block b owns edge slice [e0,e1). For each node segment, build private
// odeg/ideg histograms in LDS, dump to global hist arrays [NSLICE][N].
__global__ __launch_bounds__(256) void hist_kernel(
    const int* __restrict__ src, const int* __restrict__ dst,
    int* __restrict__ hist_o, int* __restrict__ hist_i,
    int E, int N)
{
    __shared__ int ho[SEGSZ];
    __shared__ int hi[SEGSZ];
    int b = blockIdx.x, t = threadIdx.x;
    int per = (E + NSLICE - 1) / NSLICE;
    int e0 = b * per, e1 = min(E, e0 + per);
    bool vec_ok = ((e0 & 3) == 0);

    for (int base = 0; base < N; base += SEGSZ) {
        int segn = min(SEGSZ, N - base);
        for (int j = t; j < SEGSZ; j += 256) { ho[j] = 0; hi[j] = 0; }
        __syncthreads();
        if (vec_ok) {
            int eV = e1 & ~3;
            const int4* s4 = (const int4*)src;
            const int4* d4 = (const int4*)dst;
            for (int q = (e0 >> 2) + t; q < (eV >> 2); q += 256) {
                int4 sv = s4[q];
                int4 dv = d4[q];
                unsigned u;
                u = (unsigned)(sv.x - base); if (u < (unsigned)segn) atomicAdd(&ho[u], 1);
                u = (unsigned)(sv.y - base); if (u < (unsigned)segn) atomicAdd(&ho[u], 1);
                u = (unsigned)(sv.z - base); if (u < (unsigned)segn) atomicAdd(&ho[u], 1);
                u = (unsigned)(sv.w - base); if (u < (unsigned)segn) atomicAdd(&ho[u], 1);
                u = (unsigned)(dv.x - base); if (u < (unsigned)segn) atomicAdd(&hi[u], 1);
                u = (unsigned)(dv.y - base); if (u < (unsigned)segn) atomicAdd(&hi[u], 1);
                u = (unsigned)(dv.z - base); if (u < (unsigned)segn) atomicAdd(&hi[u], 1);
                u = (unsigned)(dv.w - base); if (u < (unsigned)segn) atomicAdd(&hi[u], 1);
            }
            for (int e = eV + t; e < e1; e += 256) {
                unsigned u;
                u = (unsigned)(src[e] - base); if (u < (unsigned)segn) atomicAdd(&ho[u], 1);
                u = (unsigned)(dst[e] - base); if (u < (unsigned)segn) atomicAdd(&hi[u], 1);
            }
        } else {
            for (int e = e0 + t; e < e1; e += 256) {
                unsigned u;
                u = (unsigned)(src[e] - base); if (u < (unsigned)segn) atomicAdd(&ho[u], 1);
                u = (unsigned)(dst[e] - base); if (u < (unsigned)segn) atomicAdd(&hi[u], 1);
            }
        }
        __syncthreads();
        for (int j = t; j < segn; j += 256) {
            hist_o[(size_t)b * N + base + j] = ho[j];
            hist_i[(size_t)b * N + base + j] = hi[j];
        }
        __syncthreads();
    }
}

// ---------------- reduce: slice sums -> degrees; hist_i -> slice prefixes --
__global__ __launch_bounds__(256) void reduce_kernel(
    const int* __restrict__ hist_o, int* __restrict__ hist_i,
    int* __restrict__ ideg, float* __restrict__ rs_odeg,
    float* __restrict__ rs_ideg, int N)
{
    int d = blockIdx.x * 256 + threadIdx.x;
    if (d >= N) return;
    int run_o = 0, run_i = 0;
    #pragma unroll 4
    for (int b = 0; b < NSLICE; ++b) {
        run_o += hist_o[(size_t)b * N + d];
        int tv = hist_i[(size_t)b * N + d];
        hist_i[(size_t)b * N + d] = run_i;   // exclusive prefix over slices
        run_i += tv;
    }
    ideg[d] = run_i;
    rs_odeg[d] = rsqrtf((float)run_o);               // inf only for never-src (never read)
    rs_ideg[d] = (run_i > 0) ? rsqrtf((float)run_i) : 0.0f;
}

// ---------------- hierarchical scan of ideg -> offs (exclusive) -----------
__global__ __launch_bounds__(256) void scan1_kernel(
    const int* __restrict__ ideg, int* __restrict__ offs,
    int* __restrict__ bsum, int n)
{
    int t = threadIdx.x, lane = t & 63, wid = t >> 6;
    int i = blockIdx.x * 256 + t;
    int v = (i < n) ? ideg[i] : 0;
    int sv = wave_incl_scan(v, lane);
    __shared__ int ws[4], wso[4];
    if (lane == 63) ws[wid] = sv;
    __syncthreads();
    if (t == 0) {
        int a = 0;
        for (int w = 0; w < 4; ++w) { wso[w] = a; a += ws[w]; }
        bsum[blockIdx.x] = a;
    }
    __syncthreads();
    if (i < n) offs[i] = sv - v + wso[wid];
}

__global__ __launch_bounds__(256) void scan2_kernel(int* __restrict__ bsum, int nb)
{
    int t = threadIdx.x, lane = t & 63, wid = t >> 6;
    int v = (t < nb) ? bsum[t] : 0;
    int sv = wave_incl_scan(v, lane);
    __shared__ int ws[4], wso[4];
    if (lane == 63) ws[wid] = sv;
    __syncthreads();
    if (t == 0) {
        int a = 0;
        for (int w = 0; w < 4; ++w) { wso[w] = a; a += ws[w]; }
    }
    __syncthreads();
    if (t < nb) bsum[t] = sv - v + wso[wid];
}

__global__ __launch_bounds__(256) void scan3_kernel(
    int* __restrict__ offs, const int* __restrict__ bsum, int n)
{
    int i = blockIdx.x * 256 + threadIdx.x;
    if (i < n) offs[i] += bsum[blockIdx.x];
}

// ---------------- bucket fill via LDS cursors (no global atomics) ---------
__global__ __launch_bounds__(256) void bucket_kernel(
    const int* __restrict__ src, const int* __restrict__ dst,
    const int* __restrict__ offs, const int* __restrict__ hist_i,
    int* __restrict__ sorted_src, int E, int N)
{
    __shared__ int cur[SEGSZ];
    int b = blockIdx.x, t = threadIdx.x;
    int per = (E + NSLICE - 1) / NSLICE;
    int e0 = b * per, e1 = min(E, e0 + per);
    bool vec_ok = ((e0 & 3) == 0);

    for (int base = 0; base < N; base += SEGSZ) {
        int segn = min(SEGSZ, N - base);
        for (int j = t; j < segn; j += 256)
            cur[j] = offs[base + j] + hist_i[(size_t)b * N + base + j];
        __syncthreads();
        if (vec_ok) {
            int eV = e1 & ~3;
            const int4* d4 = (const int4*)dst;
            for (int q = (e0 >> 2) + t; q < (eV >> 2); q += 256) {
                int4 dv = d4[q];
                int e = q << 2;
                unsigned u;
                u = (unsigned)(dv.x - base);
                if (u < (unsigned)segn) sorted_src[atomicAdd(&cur[u], 1)] = src[e];
                u = (unsigned)(dv.y - base);
                if (u < (unsigned)segn) sorted_src[atomicAdd(&cur[u], 1)] = src[e + 1];
                u = (unsigned)(dv.z - base);
                if (u < (unsigned)segn) sorted_src[atomicAdd(&cur[u], 1)] = src[e + 2];
                u = (unsigned)(dv.w - base);
                if (u < (unsigned)segn) sorted_src[atomicAdd(&cur[u], 1)] = src[e + 3];
            }
            for (int e = eV + t; e < e1; e += 256) {
                unsigned u = (unsigned)(dst[e] - base);
                if (u < (unsigned)segn) sorted_src[atomicAdd(&cur[u], 1)] = src[e];
            }
        } else {
            for (int e = e0 + t; e < e1; e += 256) {
                unsigned u = (unsigned)(dst[e] - base);
                if (u < (unsigned)segn) sorted_src[atomicAdd(&cur[u], 1)] = src[e];
            }
        }
        __syncthreads();
    }
}

// ---------------- gather ----------------
__global__ __launch_bounds__(256) void gather_kernel(
    const float* __restrict__ x,
    const int* __restrict__ sorted_src,
    const int* __restrict__ offs,
    const float* __restrict__ rs_odeg,
    const float* __restrict__ rs_ideg,
    float* __restrict__ out, int N, int E)
{
    __shared__ int   sS[4][68];
    __shared__ float sW[4][68];
    int t = threadIdx.x, lane = t & 63, wid = t >> 6;
    int sub = lane >> 4, c4 = lane & 15;
    int d = blockIdx.x * 4 + wid;
    if (d >= N) return;

    int beg = offs[d];
    int end = (d + 1 < N) ? offs[d + 1] : E;
    int cnt = end - beg;
    int capped = min(cnt, 64);

    int s_l = 0; float w_l = 0.0f;
    if (lane < capped) {
        s_l = sorted_src[beg + lane];
        w_l = rs_odeg[s_l];
    }
    sS[wid][lane] = s_l;
    sW[wid][lane] = w_l;
    if (lane < 4) { sS[wid][64 + lane] = 0; sW[wid][64 + lane] = 0.0f; }

    float4 acc = make_float4(0.f, 0.f, 0.f, 0.f);
    for (int j = 0; j < capped; j += 4) {
        int jj = j + sub;
        int   s = sS[wid][jj];
        float w = sW[wid][jj];
        const float4 xv = *(const float4*)&x[(size_t)s * DD + (c4 << 2)];
        acc.x = fmaf(w, xv.x, acc.x);
        acc.y = fmaf(w, xv.y, acc.y);
        acc.z = fmaf(w, xv.z, acc.z);
        acc.w = fmaf(w, xv.w, acc.w);
    }
    for (int j = 64 + sub; j < cnt; j += 4) {
        int s = sorted_src[beg + j];
        float w = rs_odeg[s];
        const float4 xv = *(const float4*)&x[(size_t)s * DD + (c4 << 2)];
        acc.x = fmaf(w, xv.x, acc.x);
        acc.y = fmaf(w, xv.y, acc.y);
        acc.z = fmaf(w, xv.z, acc.z);
        acc.w = fmaf(w, xv.w, acc.w);
    }
    acc.x += __shfl_xor(acc.x, 16, 64); acc.x += __shfl_xor(acc.x, 32, 64);
    acc.y += __shfl_xor(acc.y, 16, 64); acc.y += __shfl_xor(acc.y, 32, 64);
    acc.z += __shfl_xor(acc.z, 16, 64); acc.z += __shfl_xor(acc.z, 32, 64);
    acc.w += __shfl_xor(acc.w, 16, 64); acc.w += __shfl_xor(acc.w, 32, 64);

    float nd = rs_ideg[d];
    if (sub == 0) {
        acc.x *= nd; acc.y *= nd; acc.z *= nd; acc.w *= nd;
        *(float4*)&out[(size_t)d * DD + (c4 << 2)] = acc;
    }
}

// ---------------- FFN (unchanged from round 3) ----------------
__global__ __launch_bounds__(256) void ffn_kernel(
    float* __restrict__ io,
    const float* __restrict__ w1, const float* __restrict__ b1,
    const float* __restrict__ w2, const float* __restrict__ b2, int n)
{
    __shared__ float sW1[4096];
    __shared__ float sW2[4096];
    __shared__ float sT[64 * 68];

    int t = threadIdx.x;
    int row0 = blockIdx.x * 64;

    const float4* w1v = (const float4*)w1;
    const float4* w2v = (const float4*)w2;
    #pragma unroll
    for (int q = 0; q < 4; ++q) {
        ((float4*)sW1)[t + q * 256] = w1v[t + q * 256];
        ((float4*)sW2)[t + q * 256] = w2v[t + q * 256];
    }
    #pragma unroll
    for (int q = 0; q < 4; ++q) {
        int idx4 = t + q * 256;
        int r = idx4 >> 4;
        int c = (idx4 & 15) << 2;
        int gr = row0 + r;
        float4 v = (gr < n) ? ((const float4*)io)[((size_t)gr * DD + c) >> 2]
                            : make_float4(0.f, 0.f, 0.f, 0.f);
        *(float4*)&sT[r * 68 + c] = v;
    }
    __syncthreads();

    int r = t >> 2;
    int cb = (t & 3) << 4;

    float acc[16];
    #pragma unroll
    for (int j = 0; j < 16; ++j) acc[j] = b1[cb + j];
    #pragma unroll 4
    for (int k = 0; k < 64; ++k) {
        float rv = sT[r * 68 + k];
        #pragma unroll
        for (int q = 0; q < 4; ++q) {
            float4 w = *(const float4*)&sW1[k * 64 + cb + (q << 2)];
            acc[q*4+0] = fmaf(rv, w.x, acc[q*4+0]);
            acc[q*4+1] = fmaf(rv, w.y, acc[q*4+1]);
            acc[q*4+2] = fmaf(rv, w.z, acc[q*4+2]);
            acc[q*4+3] = fmaf(rv, w.w, acc[q*4+3]);
        }
    }
    #pragma unroll
    for (int j = 0; j < 16; ++j) {
        float v = acc[j];
        acc[j] = 0.5f * v * (1.0f + erff(v * 0.70710678118654752f));
    }
    #pragma unroll
    for (int q = 0; q < 4; ++q)
        *(float4*)&sT[r * 68 + cb + (q << 2)] =
            make_float4(acc[q*4+0], acc[q*4+1], acc[q*4+2], acc[q*4+3]);

    #pragma unroll
    for (int j = 0; j < 16; ++j) acc[j] = b2[cb + j];
    #pragma unroll 4
    for (int k = 0; k < 64; ++k) {
        float hv = sT[r * 68 + k];
        #pragma unroll
        for (int q = 0; q < 4; ++q) {
            float4 w = *(const float4*)&sW2[k * 64 + cb + (q << 2)];
            acc[q*4+0] = fmaf(hv, w.x, acc[q*4+0]);
            acc[q*4+1] = fmaf(hv, w.y, acc[q*4+1]);
            acc[q*4+2] = fmaf(hv, w.z, acc[q*4+2]);
            acc[q*4+3] = fmaf(hv, w.w, acc[q*4+3]);
        }
    }
    int gr = row0 + r;
    if (gr < n) {
        #pragma unroll
        for (int q = 0; q < 4; ++q)
            ((float4*)io)[((size_t)gr * DD + cb + (q << 2)) >> 2] =
                make_float4(acc[q*4+0], acc[q*4+1], acc[q*4+2], acc[q*4+3]);
    }
}

extern "C" void kernel_launch(void* const* d_in, const int* in_sizes, int n_in,
                              void* d_out, int out_size, void* d_ws, size_t ws_size,
                              hipStream_t stream)
{
    const float* x    = (const float*)d_in[0];
    const int*   esrc = (const int*)d_in[1];
    const int*   edst = (const int*)d_in[2];
    const float* w1   = (const float*)d_in[3];
    const float* b1   = (const float*)d_in[4];
    const float* w2   = (const float*)d_in[5];
    const float* b2   = (const float*)d_in[6];
    float* out = (float*)d_out;

    int N = in_sizes[0] / DD;   // 50000
    int E = in_sizes[1];        // 800000
    int nb = (N + 255) / 256;   // 196

    // d_out doubles as histogram scratch: 2 * NSLICE * N ints == N * DD floats
    int* hist_o = (int*)d_out;                    // [NSLICE][N]
    int* hist_i = hist_o + (size_t)NSLICE * N;    // [NSLICE][N]

    // workspace
    int*   ideg       = (int*)d_ws;               // N
    int*   offs       = ideg + N;                 // N
    float* rs_odeg    = (float*)(offs + N);       // N
    float* rs_ideg    = rs_odeg + N;              // N
    int*   bsum       = (int*)(rs_ideg + N);      // 256
    int*   sorted_src = bsum + 256;               // E

    hist_kernel<<<NSLICE, 256, 0, stream>>>(esrc, edst, hist_o, hist_i, E, N);
    reduce_kernel<<<nb, 256, 0, stream>>>(hist_o, hist_i, ideg, rs_odeg, rs_ideg, N);
    scan1_kernel<<<nb, 256, 0, stream>>>(ideg, offs, bsum, N);
    scan2_kernel<<<1, 256, 0, stream>>>(bsum, nb);
    scan3_kernel<<<nb, 256, 0, stream>>>(offs, bsum, N);
    bucket_kernel<<<NSLICE, 256, 0, stream>>>(esrc, edst, offs, hist_i, sorted_src, E, N);
    gather_kernel<<<(N + 3) / 4, 256, 0, stream>>>(x, sorted_src, offs, rs_odeg, rs_ideg, out, N, E);
    ffn_kernel<<<(N + 63) / 64, 256, 0, stream>>>(out, w1, b1, w2, b2, N);
}

// Round 5
// 182.467 us; speedup vs baseline: 1.7144x; 1.7144x over previous
//
#include <hip/hip_runtime.h>
#include <hip/hip_bf16.h>
#include <math.h>

#define DD 64
#define SEGSZ 6400
#define NSEG 8          // SEGSZ*NSEG >= N
#define NSLICE 32

__device__ __forceinline__ int wave_incl_scan(int v, int lane) {
    #pragma unroll
    for (int d = 1; d < 64; d <<= 1) {
        int u = __shfl_up(v, d, 64);
        if (lane >= d) v += u;
    }
    return v;
}

// ---------------- histogram: grid = (slice, segment) ----------------
// Block (b,s) scans slice b's edges, histograms only nodes in segment s.
__global__ __launch_bounds__(256) void hist_kernel(
    const int* __restrict__ src, const int* __restrict__ dst,
    int* __restrict__ hist_o, int* __restrict__ hist_i,
    int E, int N)
{
    __shared__ int ho[SEGSZ];
    __shared__ int hi[SEGSZ];
    int b = blockIdx.x, s = blockIdx.y, t = threadIdx.x;
    int per = (E + NSLICE - 1) / NSLICE;
    int e0 = b * per, e1 = min(E, e0 + per);
    int base = s * SEGSZ;
    int segn = min(SEGSZ, N - base);
    if (segn <= 0) return;

    for (int j = t; j < SEGSZ; j += 256) { ho[j] = 0; hi[j] = 0; }
    __syncthreads();

    int eV = e1 & ~3;
    const int4* s4 = (const int4*)src;
    const int4* d4 = (const int4*)dst;
    for (int q = (e0 >> 2) + t; q < (eV >> 2); q += 256) {
        int4 sv = s4[q];
        int4 dv = d4[q];
        unsigned u;
        u = (unsigned)(sv.x - base); if (u < (unsigned)segn) atomicAdd(&ho[u], 1);
        u = (unsigned)(sv.y - base); if (u < (unsigned)segn) atomicAdd(&ho[u], 1);
        u = (unsigned)(sv.z - base); if (u < (unsigned)segn) atomicAdd(&ho[u], 1);
        u = (unsigned)(sv.w - base); if (u < (unsigned)segn) atomicAdd(&ho[u], 1);
        u = (unsigned)(dv.x - base); if (u < (unsigned)segn) atomicAdd(&hi[u], 1);
        u = (unsigned)(dv.y - base); if (u < (unsigned)segn) atomicAdd(&hi[u], 1);
        u = (unsigned)(dv.z - base); if (u < (unsigned)segn) atomicAdd(&hi[u], 1);
        u = (unsigned)(dv.w - base); if (u < (unsigned)segn) atomicAdd(&hi[u], 1);
    }
    for (int e = eV + t; e < e1; e += 256) {
        unsigned u;
        u = (unsigned)(src[e] - base); if (u < (unsigned)segn) atomicAdd(&ho[u], 1);
        u = (unsigned)(dst[e] - base); if (u < (unsigned)segn) atomicAdd(&hi[u], 1);
    }
    __syncthreads();
    for (int j = t; j < segn; j += 256) {
        hist_o[(size_t)b * N + base + j] = ho[j];
        hist_i[(size_t)b * N + base + j] = hi[j];
    }
}

// ---------------- reduce: slice sums -> degrees; hist_i -> slice prefixes --
__global__ __launch_bounds__(256) void reduce_kernel(
    const int* __restrict__ hist_o, int* __restrict__ hist_i,
    int* __restrict__ ideg, float* __restrict__ rs_odeg,
    float* __restrict__ rs_ideg, int N)
{
    int d = blockIdx.x * 256 + threadIdx.x;
    if (d >= N) return;
    int run_o = 0, run_i = 0;
    #pragma unroll 4
    for (int b = 0; b < NSLICE; ++b) {
        run_o += hist_o[(size_t)b * N + d];
        int tv = hist_i[(size_t)b * N + d];
        hist_i[(size_t)b * N + d] = run_i;   // exclusive prefix over slices
        run_i += tv;
    }
    ideg[d] = run_i;
    rs_odeg[d] = rsqrtf((float)run_o);               // inf only for never-src (never read)
    rs_ideg[d] = (run_i > 0) ? rsqrtf((float)run_i) : 0.0f;
}

// ---------------- hierarchical scan of ideg -> offs (exclusive) -----------
__global__ __launch_bounds__(256) void scan1_kernel(
    const int* __restrict__ ideg, int* __restrict__ offs,
    int* __restrict__ bsum, int n)
{
    int t = threadIdx.x, lane = t & 63, wid = t >> 6;
    int i = blockIdx.x * 256 + t;
    int v = (i < n) ? ideg[i] : 0;
    int sv = wave_incl_scan(v, lane);
    __shared__ int ws[4], wso[4];
    if (lane == 63) ws[wid] = sv;
    __syncthreads();
    if (t == 0) {
        int a = 0;
        for (int w = 0; w < 4; ++w) { wso[w] = a; a += ws[w]; }
        bsum[blockIdx.x] = a;
    }
    __syncthreads();
    if (i < n) offs[i] = sv - v + wso[wid];
}

__global__ __launch_bounds__(256) void scan2_kernel(int* __restrict__ bsum, int nb)
{
    int t = threadIdx.x, lane = t & 63, wid = t >> 6;
    int v = (t < nb) ? bsum[t] : 0;
    int sv = wave_incl_scan(v, lane);
    __shared__ int ws[4], wso[4];
    if (lane == 63) ws[wid] = sv;
    __syncthreads();
    if (t == 0) {
        int a = 0;
        for (int w = 0; w < 4; ++w) { wso[w] = a; a += ws[w]; }
    }
    __syncthreads();
    if (t < nb) bsum[t] = sv - v + wso[wid];
}

__global__ __launch_bounds__(256) void scan3_kernel(
    int* __restrict__ offs, const int* __restrict__ bsum, int n)
{
    int i = blockIdx.x * 256 + threadIdx.x;
    if (i < n) offs[i] += bsum[blockIdx.x];
}

// ---------------- bucket fill: grid = (slice, segment), LDS cursors -------
__global__ __launch_bounds__(256) void bucket_kernel(
    const int* __restrict__ src, const int* __restrict__ dst,
    const int* __restrict__ offs, const int* __restrict__ hist_i,
    int* __restrict__ sorted_src, int E, int N)
{
    __shared__ int cur[SEGSZ];
    int b = blockIdx.x, s = blockIdx.y, t = threadIdx.x;
    int per = (E + NSLICE - 1) / NSLICE;
    int e0 = b * per, e1 = min(E, e0 + per);
    int base = s * SEGSZ;
    int segn = min(SEGSZ, N - base);
    if (segn <= 0) return;

    for (int j = t; j < segn; j += 256)
        cur[j] = offs[base + j] + hist_i[(size_t)b * N + base + j];
    __syncthreads();

    int eV = e1 & ~3;
    const int4* s4 = (const int4*)src;
    const int4* d4 = (const int4*)dst;
    for (int q = (e0 >> 2) + t; q < (eV >> 2); q += 256) {
        int4 dv = d4[q];
        int4 sv = s4[q];
        unsigned u;
        u = (unsigned)(dv.x - base);
        if (u < (unsigned)segn) sorted_src[atomicAdd(&cur[u], 1)] = sv.x;
        u = (unsigned)(dv.y - base);
        if (u < (unsigned)segn) sorted_src[atomicAdd(&cur[u], 1)] = sv.y;
        u = (unsigned)(dv.z - base);
        if (u < (unsigned)segn) sorted_src[atomicAdd(&cur[u], 1)] = sv.z;
        u = (unsigned)(dv.w - base);
        if (u < (unsigned)segn) sorted_src[atomicAdd(&cur[u], 1)] = sv.w;
    }
    for (int e = eV + t; e < e1; e += 256) {
        unsigned u = (unsigned)(dst[e] - base);
        if (u < (unsigned)segn) sorted_src[atomicAdd(&cur[u], 1)] = src[e];
    }
}

// ---------------- gather ----------------
// one wave per dst node; 8-edge unroll (two independent row loads in flight)
__global__ __launch_bounds__(256) void gather_kernel(
    const float* __restrict__ x,
    const int* __restrict__ sorted_src,
    const int* __restrict__ offs,
    const float* __restrict__ rs_odeg,
    const float* __restrict__ rs_ideg,
    float* __restrict__ out, int N, int E)
{
    __shared__ int   sS[4][68];
    __shared__ float sW[4][68];
    int t = threadIdx.x, lane = t & 63, wid = t >> 6;
    int sub = lane >> 4, c4 = lane & 15;
    int d = blockIdx.x * 4 + wid;
    if (d >= N) return;

    int beg = offs[d];
    int end = (d + 1 < N) ? offs[d + 1] : E;
    int cnt = end - beg;
    int capped = min(cnt, 64);

    int s_l = 0; float w_l = 0.0f;
    if (lane < capped) {
        s_l = sorted_src[beg + lane];
        w_l = rs_odeg[s_l];
    }
    sS[wid][lane] = s_l;
    sW[wid][lane] = w_l;
    if (lane < 4) { sS[wid][64 + lane] = 0; sW[wid][64 + lane] = 0.0f; }

    float4 acc = make_float4(0.f, 0.f, 0.f, 0.f);
    int j = 0;
    for (; j + 8 <= capped; j += 8) {
        int jj0 = j + sub;
        int jj1 = j + 4 + sub;
        int   sA = sS[wid][jj0];
        int   sB = sS[wid][jj1];
        float wA = sW[wid][jj0];
        float wB = sW[wid][jj1];
        const float4 xa = *(const float4*)&x[(size_t)sA * DD + (c4 << 2)];
        const float4 xb = *(const float4*)&x[(size_t)sB * DD + (c4 << 2)];
        acc.x = fmaf(wA, xa.x, acc.x); acc.y = fmaf(wA, xa.y, acc.y);
        acc.z = fmaf(wA, xa.z, acc.z); acc.w = fmaf(wA, xa.w, acc.w);
        acc.x = fmaf(wB, xb.x, acc.x); acc.y = fmaf(wB, xb.y, acc.y);
        acc.z = fmaf(wB, xb.z, acc.z); acc.w = fmaf(wB, xb.w, acc.w);
    }
    for (; j < capped; j += 4) {
        int jj = j + sub;                 // pads [64..67] are zero-weight
        int   s = sS[wid][jj];
        float w = sW[wid][jj];
        const float4 xv = *(const float4*)&x[(size_t)s * DD + (c4 << 2)];
        acc.x = fmaf(w, xv.x, acc.x); acc.y = fmaf(w, xv.y, acc.y);
        acc.z = fmaf(w, xv.z, acc.z); acc.w = fmaf(w, xv.w, acc.w);
    }
    for (int jt = 64 + sub; jt < cnt; jt += 4) {   // rare: degree > 64
        int s = sorted_src[beg + jt];
        float w = rs_odeg[s];
        const float4 xv = *(const float4*)&x[(size_t)s * DD + (c4 << 2)];
        acc.x = fmaf(w, xv.x, acc.x); acc.y = fmaf(w, xv.y, acc.y);
        acc.z = fmaf(w, xv.z, acc.z); acc.w = fmaf(w, xv.w, acc.w);
    }
    acc.x += __shfl_xor(acc.x, 16, 64); acc.x += __shfl_xor(acc.x, 32, 64);
    acc.y += __shfl_xor(acc.y, 16, 64); acc.y += __shfl_xor(acc.y, 32, 64);
    acc.z += __shfl_xor(acc.z, 16, 64); acc.z += __shfl_xor(acc.z, 32, 64);
    acc.w += __shfl_xor(acc.w, 16, 64); acc.w += __shfl_xor(acc.w, 32, 64);

    float nd = rs_ideg[d];
    if (sub == 0) {
        acc.x *= nd; acc.y *= nd; acc.z *= nd; acc.w *= nd;
        *(float4*)&out[(size_t)d * DD + (c4 << 2)] = acc;
    }
}

// ---------------- FFN (unchanged) ----------------
__global__ __launch_bounds__(256) void ffn_kernel(
    float* __restrict__ io,
    const float* __restrict__ w1, const float* __restrict__ b1,
    const float* __restrict__ w2, const float* __restrict__ b2, int n)
{
    __shared__ float sW1[4096];
    __shared__ float sW2[4096];
    __shared__ float sT[64 * 68];

    int t = threadIdx.x;
    int row0 = blockIdx.x * 64;

    const float4* w1v = (const float4*)w1;
    const float4* w2v = (const float4*)w2;
    #pragma unroll
    for (int q = 0; q < 4; ++q) {
        ((float4*)sW1)[t + q * 256] = w1v[t + q * 256];
        ((float4*)sW2)[t + q * 256] = w2v[t + q * 256];
    }
    #pragma unroll
    for (int q = 0; q < 4; ++q) {
        int idx4 = t + q * 256;
        int r = idx4 >> 4;
        int c = (idx4 & 15) << 2;
        int gr = row0 + r;
        float4 v = (gr < n) ? ((const float4*)io)[((size_t)gr * DD + c) >> 2]
                            : make_float4(0.f, 0.f, 0.f, 0.f);
        *(float4*)&sT[r * 68 + c] = v;
    }
    __syncthreads();

    int r = t >> 2;
    int cb = (t & 3) << 4;

    float acc[16];
    #pragma unroll
    for (int j = 0; j < 16; ++j) acc[j] = b1[cb + j];
    #pragma unroll 4
    for (int k = 0; k < 64; ++k) {
        float rv = sT[r * 68 + k];
        #pragma unroll
        for (int q = 0; q < 4; ++q) {
            float4 w = *(const float4*)&sW1[k * 64 + cb + (q << 2)];
            acc[q*4+0] = fmaf(rv, w.x, acc[q*4+0]);
            acc[q*4+1] = fmaf(rv, w.y, acc[q*4+1]);
            acc[q*4+2] = fmaf(rv, w.z, acc[q*4+2]);
            acc[q*4+3] = fmaf(rv, w.w, acc[q*4+3]);
        }
    }
    #pragma unroll
    for (int j = 0; j < 16; ++j) {
        float v = acc[j];
        acc[j] = 0.5f * v * (1.0f + erff(v * 0.70710678118654752f));
    }
    #pragma unroll
    for (int q = 0; q < 4; ++q)
        *(float4*)&sT[r * 68 + cb + (q << 2)] =
            make_float4(acc[q*4+0], acc[q*4+1], acc[q*4+2], acc[q*4+3]);

    #pragma unroll
    for (int j = 0; j < 16; ++j) acc[j] = b2[cb + j];
    #pragma unroll 4
    for (int k = 0; k < 64; ++k) {
        float hv = sT[r * 68 + k];
        #pragma unroll
        for (int q = 0; q < 4; ++q) {
            float4 w = *(const float4*)&sW2[k * 64 + cb + (q << 2)];
            acc[q*4+0] = fmaf(hv, w.x, acc[q*4+0]);
            acc[q*4+1] = fmaf(hv, w.y, acc[q*4+1]);
            acc[q*4+2] = fmaf(hv, w.z, acc[q*4+2]);
            acc[q*4+3] = fmaf(hv, w.w, acc[q*4+3]);
        }
    }
    int gr = row0 + r;
    if (gr < n) {
        #pragma unroll
        for (int q = 0; q < 4; ++q)
            ((float4*)io)[((size_t)gr * DD + cb + (q << 2)) >> 2] =
                make_float4(acc[q*4+0], acc[q*4+1], acc[q*4+2], acc[q*4+3]);
    }
}

extern "C" void kernel_launch(void* const* d_in, const int* in_sizes, int n_in,
                              void* d_out, int out_size, void* d_ws, size_t ws_size,
                              hipStream_t stream)
{
    const float* x    = (const float*)d_in[0];
    const int*   esrc = (const int*)d_in[1];
    const int*   edst = (const int*)d_in[2];
    const float* w1   = (const float*)d_in[3];
    const float* b1   = (const float*)d_in[4];
    const float* w2   = (const float*)d_in[5];
    const float* b2   = (const float*)d_in[6];
    float* out = (float*)d_out;

    int N = in_sizes[0] / DD;   // 50000
    int E = in_sizes[1];        // 800000
    int nb = (N + 255) / 256;   // 196

    // d_out doubles as histogram scratch: 2 * NSLICE * N ints == N * DD floats
    int* hist_o = (int*)d_out;                    // [NSLICE][N]
    int* hist_i = hist_o + (size_t)NSLICE * N;    // [NSLICE][N]

    // workspace
    int*   ideg       = (int*)d_ws;               // N
    int*   offs       = ideg + N;                 // N
    float* rs_odeg    = (float*)(offs + N);       // N
    float* rs_ideg    = rs_odeg + N;              // N
    int*   bsum       = (int*)(rs_ideg + N);      // 256
    int*   sorted_src = bsum + 256;               // E

    hist_kernel<<<dim3(NSLICE, NSEG), 256, 0, stream>>>(esrc, edst, hist_o, hist_i, E, N);
    reduce_kernel<<<nb, 256, 0, stream>>>(hist_o, hist_i, ideg, rs_odeg, rs_ideg, N);
    scan1_kernel<<<nb, 256, 0, stream>>>(ideg, offs, bsum, N);
    scan2_kernel<<<1, 256, 0, stream>>>(bsum, nb);
    scan3_kernel<<<nb, 256, 0, stream>>>(offs, bsum, N);
    bucket_kernel<<<dim3(NSLICE, NSEG), 256, 0, stream>>>(esrc, edst, offs, hist_i, sorted_src, E, N);
    gather_kernel<<<(N + 3) / 4, 256, 0, stream>>>(x, sorted_src, offs, rs_odeg, rs_ideg, out, N, E);
    ffn_kernel<<<(N + 63) / 64, 256, 0, stream>>>(out, w1, b1, w2, b2, N);
}